// Round 5
// baseline (160.452 us; speedup 1.0000x reference)
//
#include <hip/hip_runtime.h>
#include <math.h>

// SpectralConv2d: out = idht2( mix( dht2(x)[:, :, :32, :32], W ) ) / S^2
// x:  [32][64][128][128] f32   weights1: [64][64][32][32] f32
// out:[32][64][128][128] f32
//
// M is the recursive pseudo-Hartley operator (NOT plain cas(2pi kn/N)):
//   M[k,n] = prod over levels (size Nj = 128,64,...,2):
//     if bit_j(n): (k_j < Nj/2 ? +1 : -1) * cas(2*pi*(k_j mod Nj/2)/Nj), else 1
//     with k_{j+1} = k_j mod (Nj/2).
//
// Pipeline (6 dispatches):
//   k_prep (build M/MT + transpose W) -> k_fwd (Xh[bi][m]) ->
//   t_xh (Xh_t[m][i*32+b]) -> k_mix4 (pair-block, both modes per block) ->
//   t_blk (blk[bo][m]) -> k_inv.

#define SS   128
#define MD   32
#define NBAT 32
#define CI   64
#define CO   64

#define TWO_PI 6.2831853071795864769

// ws layout (floats). blk_t aliases Xh (dead after t_xh); blk aliases Xh_t
// (dead after k_mix4). Total ~32.1 MB.
static const size_t OFF_M    = 0;
static const size_t OFF_MT   = 16384;
static const size_t OFF_XH   = 32768;                    // 2048*1024
static const size_t OFF_XHT  = 32768 + 2097152;          // 2048*1024
static const size_t OFF_WT   = 32768 + 2 * 2097152;      // 4096*1024
static const size_t OFF_BLKT = OFF_XH;                   // alias
static const size_t OFF_BLK  = OFF_XHT;                  // alias

// blocks 0..63: build M/MT (256 entries each).
// blocks 64..4159: transpose wgt[(i*64+o)][m] -> Wt[m][i*64+o] in 32x32 tiles.
__global__ __launch_bounds__(256) void k_prep(const float* __restrict__ wgt,
                                              float* __restrict__ M,
                                              float* __restrict__ MT,
                                              float* __restrict__ Wt) {
    const int bid = blockIdx.x;
    const int t   = threadIdx.x;
    if (bid < 64) {
        int idx = bid * 256 + t;        // 16384 entries
        int k = idx >> 7, n = idx & 127;
        float prod = 1.f;
        int kk = k, nn = n;
        for (int Nj = SS; Nj > 1; Nj >>= 1) {
            int half = Nj >> 1;
            int k1 = kk & (half - 1);
            if (nn & 1) {
                double ang = (TWO_PI / (double)Nj) * (double)k1;
                float cas = (float)(cos(ang) + sin(ang));
                prod *= (kk < half) ? cas : -cas;
            }
            kk = k1;
            nn >>= 1;
        }
        M[idx] = prod;
        MT[n * 128 + k] = prod;
        return;
    }
    __shared__ float tile[32][33];
    const int b2  = bid - 64;
    const int mt  = b2 & 31;
    const int iot = b2 >> 5;             // 0..127
    const int tx = t & 31;
    const int ty = t >> 5;
#pragma unroll
    for (int j = 0; j < 4; ++j) {
        int r = ty + 8 * j;
        tile[r][tx] = wgt[(iot * 32 + r) * 1024 + mt * 32 + tx];
    }
    __syncthreads();
#pragma unroll
    for (int j = 0; j < 4; ++j) {
        int r = ty + 8 * j;
        Wt[(mt * 32 + r) * 4096 + iot * 32 + tx] = tile[tx][r];
    }
}

// Forward: per (b,c) block: Xh[k][l] = sum_{h,w} M[k][h]*M[l][w]*x[h][w], k,l<32
__global__ __launch_bounds__(256) void k_fwd(const float* __restrict__ x,
                                             const float* __restrict__ MT,
                                             float* __restrict__ Xh) {
    const int bc = blockIdx.x;
    const float* xp = x + (size_t)bc * (SS * SS);
    const int t = threadIdx.x;
    __shared__ float Ys[MD][SS + 1];   // Y[k][w], padded: bank = (k+w)%32

    const int w  = t & 127;
    const int kh = __builtin_amdgcn_readfirstlane(t >> 7);   // 0,0,1,1 per wave
    {
        float acc[16];
#pragma unroll
        for (int j = 0; j < 16; ++j) acc[j] = 0.f;
#pragma unroll 4
        for (int h = 0; h < SS; ++h) {
            float xv = xp[h * SS + w];                  // coalesced
            const float* mrow = MT + h * 128 + kh * 16; // uniform -> s_load
#pragma unroll
            for (int j = 0; j < 16; ++j)
                acc[j] = fmaf(mrow[j], xv, acc[j]);
        }
#pragma unroll
        for (int j = 0; j < 16; ++j) Ys[kh * 16 + j][w] = acc[j];
    }
    __syncthreads();

    // Phase 2: Z[k][l] = sum_w Y[k][w]*M[l][w]. All lanes useful: dup halves
    // split the ww range; one shfl_xor(32) combine per accumulator.
    const int k   = t & 31;
    const int dup = (t >> 5) & 1;
    const int wid = __builtin_amdgcn_readfirstlane(t >> 6);  // 0..3
    float z[8];
#pragma unroll
    for (int j = 0; j < 8; ++j) z[j] = 0.f;
    const int w0 = dup * 64;
#pragma unroll 8
    for (int ww = w0; ww < w0 + 64; ++ww) {
        float yv = Ys[k][ww];                        // conflict-free broadcast
        const float* mcol = MT + ww * 128 + wid * 8; // uniform -> s_load
#pragma unroll
        for (int j = 0; j < 8; ++j)
            z[j] = fmaf(mcol[j], yv, z[j]);
    }
#pragma unroll
    for (int j = 0; j < 8; ++j)
        z[j] += __shfl_xor(z[j], 32);                // combine dup halves
    if (dup == 0) {
        float* outp = Xh + (size_t)bc * (MD * MD) + k * MD + wid * 8;
#pragma unroll
        for (int j = 0; j < 8; ++j) outp[j] = z[j];
    }
}

// Transpose Xh[(b*64+i)][m] -> Xh_t[m][i*32+b].  2048 blocks: (i, m-tile).
__global__ __launch_bounds__(256) void t_xh(const float* __restrict__ Xh,
                                            float* __restrict__ Xh_t) {
    __shared__ float tile[32][33];
    const int i  = blockIdx.x & 63;
    const int mt = blockIdx.x >> 6;      // 0..31
    const int tx = threadIdx.x & 31;
    const int ty = threadIdx.x >> 5;     // 0..7
#pragma unroll
    for (int j = 0; j < 4; ++j) {
        int b = ty + 8 * j;
        tile[b][tx] = Xh[(b * 64 + i) * 1024 + mt * 32 + tx];
    }
    __syncthreads();
#pragma unroll
    for (int j = 0; j < 4; ++j) {
        int row = ty + 8 * j;
        Xh_t[(mt * 32 + row) * 2048 + i * 32 + tx] = tile[tx][row];
    }
}

// Mix, pair-block: block = mode-pair (m, nm). Outputs BOTH modes:
//   out[m]  = x1*We + x1n*Wo,  out[nm] = x1n*We - x1*Wo
//   (We = 0.5*(w[m]+w[nm]), Wo = 0.5*(w[m]-w[nm]))
__global__ __launch_bounds__(256) void k_mix4(const float* __restrict__ Xh_t,
                                              const float* __restrict__ Wt,
                                              float* __restrict__ blk_t) {
    const int m  = blockIdx.x;           // 0..1023
    const int xm = m >> 5, ym = m & 31;
    const int nm = (((32 - xm) & 31) << 5) | ((32 - ym) & 31);
    if (m > nm) return;
    const int t = threadIdx.x;

    __shared__ float Xs[2][64][32];      // [mode][i][b], 16 KB

    {   // stage both mode rows (2048 floats each) as float4
        const float4* xm4 = (const float4*)(Xh_t + m * 2048);
        const float4* xn4 = (const float4*)(Xh_t + nm * 2048);
        float4* s0 = (float4*)&Xs[0][0][0];
        float4* s1 = (float4*)&Xs[1][0][0];
        s0[t]       = xm4[t];
        s0[t + 256] = xm4[t + 256];
        s1[t]       = xn4[t];
        s1[t + 256] = xn4[t + 256];
    }
    __syncthreads();

    const int o  = t & 63;
    const int bq = t >> 6;               // wave-uniform b-octet
    const float* wpm = Wt + m * 4096 + o;
    const float* wpn = Wt + nm * 4096 + o;

    float am[8], an[8];
#pragma unroll
    for (int j = 0; j < 8; ++j) { am[j] = 0.f; an[j] = 0.f; }

#pragma unroll 4
    for (int i = 0; i < 64; ++i) {
        float wm = wpm[i * 64];          // coalesced 256B, L1 hit across waves
        float wn = wpn[i * 64];
        float we = 0.5f * (wm + wn);
        float wo = 0.5f * (wm - wn);
        const float* xr  = &Xs[0][i][bq * 8];   // wave-uniform -> broadcast
        const float* xrn = &Xs[1][i][bq * 8];
#pragma unroll
        for (int j = 0; j < 8; ++j) {
            float x1  = xr[j];
            float x1n = xrn[j];
            am[j] = fmaf(x1, we, fmaf(x1n, wo, am[j]));
            an[j] = fmaf(x1n, we, fmaf(x1, -wo, an[j]));
        }
    }

    float* om = blk_t + m * 2048 + o;
    float* on = blk_t + nm * 2048 + o;
#pragma unroll
    for (int j = 0; j < 8; ++j) {
        int b = bq * 8 + j;
        om[b * 64] = am[j];              // coalesced 256B rows
        on[b * 64] = an[j];
    }
}

// Transpose blk_t[m][bo] -> blk[bo][m].  2048 blocks: (bo-tile, m-tile).
__global__ __launch_bounds__(256) void t_blk(const float* __restrict__ blk_t,
                                             float* __restrict__ blk) {
    __shared__ float tile[32][33];
    const int mt  = blockIdx.x & 31;
    const int bot = blockIdx.x >> 5;     // 0..63
    const int tx = threadIdx.x & 31;
    const int ty = threadIdx.x >> 5;
#pragma unroll
    for (int j = 0; j < 4; ++j) {
        int r = ty + 8 * j;
        tile[r][tx] = blk_t[(mt * 32 + r) * 2048 + bot * 32 + tx];
    }
    __syncthreads();
#pragma unroll
    for (int j = 0; j < 4; ++j) {
        int r = ty + 8 * j;
        blk[(bot * 32 + r) * 1024 + mt * 32 + tx] = tile[tx][r];
    }
}

// Inverse: per (b,o) block:
//   T[r][l]   = (1/16384) * sum_{h<32} M[r][h] * blk[h][l]
//   out[r][c] = sum_{l<32} T[r][l] * M[c][l]
__global__ __launch_bounds__(256) void k_inv(const float* __restrict__ blk,
                                             const float* __restrict__ M,
                                             const float* __restrict__ MT,
                                             float* __restrict__ out) {
    const int bo = blockIdx.x;
    const int t  = threadIdx.x;
    __shared__ float smem[8448];       // Mcs[128][33] | Ts[128][33]; reused as outS[128][65]
    float* Mcs  = smem;
    float* Ts   = smem + 4224;
    float* outS = smem;

#pragma unroll
    for (int j = 0; j < 16; ++j) {
        int idx = t + j * 256;
        int r = idx >> 5, h = idx & 31;
        Mcs[r * 33 + h] = M[r * 128 + h] * (1.f / 16384.f);
    }
    __syncthreads();

    const int r  = t & 127;
    const int rh = __builtin_amdgcn_readfirstlane(t >> 7);   // 0 or 1

    {
        const float* bp = blk + (size_t)bo * (MD * MD);
        float acc[16];
#pragma unroll
        for (int j = 0; j < 16; ++j) acc[j] = 0.f;
#pragma unroll 4
        for (int h = 0; h < MD; ++h) {
            float mc = Mcs[r * 33 + h];
            const float* brow = bp + h * MD + rh * 16;   // uniform -> s_load_x8
#pragma unroll
            for (int j = 0; j < 16; ++j)
                acc[j] = fmaf(brow[j], mc, acc[j]);
        }
#pragma unroll
        for (int j = 0; j < 16; ++j) Ts[r * 33 + rh * 16 + j] = acc[j];
    }
    __syncthreads();

    float acc[64];
#pragma unroll
    for (int j = 0; j < 64; ++j) acc[j] = 0.f;
#pragma unroll 2
    for (int l = 0; l < MD; ++l) {
        float tv = Ts[r * 33 + l];                   // per-lane, conflict-free
        const float* mt = MT + l * 128 + rh * 64;    // uniform -> s_load_x16
#pragma unroll
        for (int j = 0; j < 64; ++j)
            acc[j] = fmaf(mt[j], tv, acc[j]);
    }

    float* op = out + (size_t)bo * (SS * SS);
    for (int rr = 0; rr < 2; ++rr) {
        __syncthreads();
        if (rh == rr) {
#pragma unroll
            for (int j = 0; j < 64; ++j) outS[r * 65 + j] = acc[j];
        }
        __syncthreads();
        const int cc = t & 63;
        const int r0 = t >> 6;
#pragma unroll
        for (int j = 0; j < 32; ++j) {
            int rrow = r0 + 4 * j;
            op[rrow * SS + rr * 64 + cc] = outS[rrow * 65 + cc];
        }
    }
}

extern "C" void kernel_launch(void* const* d_in, const int* in_sizes, int n_in,
                              void* d_out, int out_size, void* d_ws, size_t ws_size,
                              hipStream_t stream) {
    const float* x   = (const float*)d_in[0];
    const float* wgt = (const float*)d_in[1];
    float* outp = (float*)d_out;
    float* ws   = (float*)d_ws;

    float* M     = ws + OFF_M;
    float* MT    = ws + OFF_MT;
    float* Xh    = ws + OFF_XH;
    float* Xh_t  = ws + OFF_XHT;
    float* Wt    = ws + OFF_WT;
    float* blk_t = ws + OFF_BLKT;   // aliases Xh (dead after t_xh)
    float* blk   = ws + OFF_BLK;    // aliases Xh_t (dead after k_mix4)

    k_prep <<<4160, 256, 0, stream>>>(wgt, M, MT, Wt);
    k_fwd  <<<2048, 256, 0, stream>>>(x, MT, Xh);
    t_xh   <<<2048, 256, 0, stream>>>(Xh, Xh_t);
    k_mix4 <<<1024, 256, 0, stream>>>(Xh_t, Wt, blk_t);
    t_blk  <<<2048, 256, 0, stream>>>(blk_t, blk);
    k_inv  <<<2048, 256, 0, stream>>>(blk, M, MT, outp);
}

// Round 6
// 122.424 us; speedup vs baseline: 1.3106x; 1.3106x over previous
//
#include <hip/hip_runtime.h>
#include <math.h>

// SpectralConv2d: out = idht2( mix( dht2(x)[:, :, :32, :32], W ) ) / S^2
// x:  [32][64][128][128] f32   weights1: [64][64][32][32] f32
// out:[32][64][128][128] f32
//
// M is the recursive pseudo-Hartley operator (NOT plain cas(2pi kn/N)):
//   M[k,n] = prod over levels (size Nj = 128,64,...,2):
//     if bit_j(n): (k_j < Nj/2 ? +1 : -1) * cas(2*pi*(k_j mod Nj/2)/Nj), else 1
//     with k_{j+1} = k_j mod (Nj/2).
//
// Pipeline: k_prep (M/MT + W-transpose + bf16 hi/lo MFMA fragment tables) ->
//   k_fwd2 (MFMA bf16-split: Y' = X*M32^T then Z = M32*Y') -> t_xh ->
//   k_mix4 -> t_blk -> k_inv.

#define SS   128
#define MD   32
#define NBAT 32
#define CI   64
#define CO   64

#define TWO_PI 6.2831853071795864769

typedef __attribute__((ext_vector_type(8))) short bf16x8;
typedef __attribute__((ext_vector_type(4))) float f32x4;

// ws layout (floats). blk_t aliases Xh; blk aliases Xh_t. ~33.7 MB.
static const size_t OFF_M    = 0;
static const size_t OFF_MT   = 16384;
static const size_t OFF_XH   = 32768;                    // 2048*1024
static const size_t OFF_XHT  = 32768 + 2097152;          // 2048*1024
static const size_t OFF_WT   = 32768 + 2 * 2097152;      // 4096*1024
static const size_t OFF_BLKT = OFF_XH;                   // alias
static const size_t OFF_BLK  = OFF_XHT;                  // alias
static const size_t OFF_MFH  = OFF_WT + 4194304;         // 4096 ushort = 2048 floats
static const size_t OFF_MFL  = OFF_MFH + 2048;           // 4096 ushort

__device__ inline float m_entry(int k, int n) {
    float prod = 1.f;
    int kk = k, nn = n;
    for (int Nj = SS; Nj > 1; Nj >>= 1) {
        int half = Nj >> 1;
        int k1 = kk & (half - 1);
        if (nn & 1) {
            double ang = (TWO_PI / (double)Nj) * (double)k1;
            float cas = (float)(cos(ang) + sin(ang));
            prod *= (kk < half) ? cas : -cas;
        }
        kk = k1;
        nn >>= 1;
    }
    return prod;
}

__device__ inline unsigned short f2bf(float f) {
    unsigned u = __float_as_uint(f);
    return (unsigned short)((u + 0x7FFF + ((u >> 16) & 1)) >> 16);
}
__device__ inline float bf2f(unsigned short h) {
    return __uint_as_float((unsigned)h << 16);
}
__device__ inline void split2(float a, float b, unsigned& hi, unsigned& lo) {
    unsigned short ah = f2bf(a), bh = f2bf(b);
    hi = (unsigned)ah | ((unsigned)bh << 16);
    lo = (unsigned)f2bf(a - bf2f(ah)) | ((unsigned)f2bf(b - bf2f(bh)) << 16);
}

// blocks 0..63: build M/MT.  blocks 64..4159: transpose W -> Wt.
// blocks 4160..4175: MFMA fragment tables for M32 (bf16 hi/lo):
//   entry(tt,s,lane,j) = M[tt*16 + (lane&15)][s*32 + (lane>>4)*8 + j]
//   (serves BOTH step-1 B (col=lane&15, k contiguous) and step-2 A.)
__global__ __launch_bounds__(256) void k_prep(const float* __restrict__ wgt,
                                              float* __restrict__ M,
                                              float* __restrict__ MT,
                                              float* __restrict__ Wt,
                                              unsigned short* __restrict__ MFH,
                                              unsigned short* __restrict__ MFL) {
    const int bid = blockIdx.x;
    const int t   = threadIdx.x;
    if (bid < 64) {
        int idx = bid * 256 + t;
        int k = idx >> 7, n = idx & 127;
        float prod = m_entry(k, n);
        M[idx] = prod;
        MT[n * 128 + k] = prod;
        return;
    }
    if (bid >= 4160) {
        int idx2 = (bid - 4160) * 256 + t;       // 0..4095
        int j    = idx2 & 7;
        int lane = (idx2 >> 3) & 63;
        int s    = (idx2 >> 9) & 3;
        int tt   = idx2 >> 11;
        int kq   = tt * 16 + (lane & 15);
        int nq   = s * 32 + ((lane >> 4) << 3) + j;
        float f  = m_entry(kq, nq);
        unsigned short hi = f2bf(f);
        MFH[idx2] = hi;
        MFL[idx2] = f2bf(f - bf2f(hi));
        return;
    }
    __shared__ float tile[32][33];
    const int b2  = bid - 64;
    const int mt  = b2 & 31;
    const int iot = b2 >> 5;
    const int tx = t & 31;
    const int ty = t >> 5;
#pragma unroll
    for (int j = 0; j < 4; ++j) {
        int r = ty + 8 * j;
        tile[r][tx] = wgt[(iot * 32 + r) * 1024 + mt * 32 + tx];
    }
    __syncthreads();
#pragma unroll
    for (int j = 0; j < 4; ++j) {
        int r = ty + 8 * j;
        Wt[(mt * 32 + r) * 4096 + iot * 32 + tx] = tile[tx][r];
    }
}

// Forward via MFMA bf16 hi/lo split. Per block = one (b,c) plane.
//   step 1: Y'[h][l] = sum_w X[h][w] * M32[l][w]   (K=w, A=X contiguous-K)
//   step 2: Z[k][l]  = sum_h M32[k][h] * Y'[h][l]  (K=h, A=M table, B=Y bounce)
// X staged in w-panels [128h][32w] bf16 hi/lo, XOR-swizzled, double-buffered.
__global__ __launch_bounds__(256, 3) void k_fwd2(const float* __restrict__ x,
                                                 const unsigned short* __restrict__ MFH,
                                                 const unsigned short* __restrict__ MFL,
                                                 float* __restrict__ Xh) {
    const int bc = blockIdx.x;
    const float* xp = x + (size_t)bc * 16384;
    const int t = threadIdx.x;
    const int lane = t & 63, wid = t >> 6;
    const int l15 = lane & 15, g = lane >> 4;

    __shared__ unsigned short Pan[2][2][4096];   // [buf][hi/lo], swizzled [h][w']
    __shared__ unsigned short Ybf[2][32 * 136];  // [hi/lo][l][136 h-slots]

    const int sh0 = t >> 3, swq = t & 7;         // staging coords

    {   // stage panel 0
#pragma unroll
        for (int q = 0; q < 4; ++q) {
            int h = sh0 + 32 * q;
            float4 v = *(const float4*)(xp + h * 128 + swq * 4);
            unsigned h01, l01, h23, l23;
            split2(v.x, v.y, h01, l01);
            split2(v.z, v.w, h23, l23);
            int i8 = h * 8 + (swq ^ ((h & 3) << 1));
            ((uint2*)&Pan[0][0][0])[i8] = make_uint2(h01, h23);
            ((uint2*)&Pan[0][1][0])[i8] = make_uint2(l01, l23);
        }
    }

    f32x4 acc[2][2] = {};                        // [hh][lt]
    const int hbase = wid * 32;

    for (int s = 0; s < 4; ++s) {
        __syncthreads();
        const int cur = s & 1, nxt = cur ^ 1;
        float4 pre[4];
        if (s < 3) {                              // issue next-panel loads early
#pragma unroll
            for (int q = 0; q < 4; ++q)
                pre[q] = *(const float4*)(xp + (sh0 + 32 * q) * 128 + (s + 1) * 32 + swq * 4);
        }
        bf16x8 Bh[2], Bl[2];
#pragma unroll
        for (int lt = 0; lt < 2; ++lt) {
            int bidx = (lt * 4 + s) * 64 + lane;  // L1-hot 16KB table
            Bh[lt] = ((const bf16x8*)MFH)[bidx];
            Bl[lt] = ((const bf16x8*)MFL)[bidx];
        }
#pragma unroll
        for (int hh = 0; hh < 2; ++hh) {
            int h = hbase + hh * 16 + l15;
            int aidx = h * 4 + (g ^ (h & 3));     // swizzled b128
            bf16x8 Ah = ((const bf16x8*)&Pan[cur][0][0])[aidx];
            bf16x8 Al = ((const bf16x8*)&Pan[cur][1][0])[aidx];
#pragma unroll
            for (int lt = 0; lt < 2; ++lt) {
                acc[hh][lt] = __builtin_amdgcn_mfma_f32_16x16x32_bf16(Ah, Bh[lt], acc[hh][lt], 0, 0, 0);
                acc[hh][lt] = __builtin_amdgcn_mfma_f32_16x16x32_bf16(Ah, Bl[lt], acc[hh][lt], 0, 0, 0);
                acc[hh][lt] = __builtin_amdgcn_mfma_f32_16x16x32_bf16(Al, Bh[lt], acc[hh][lt], 0, 0, 0);
            }
        }
        if (s < 3) {                              // write next panel
#pragma unroll
            for (int q = 0; q < 4; ++q) {
                int h = sh0 + 32 * q;
                unsigned h01, l01, h23, l23;
                split2(pre[q].x, pre[q].y, h01, l01);
                split2(pre[q].z, pre[q].w, h23, l23);
                int i8 = h * 8 + (swq ^ ((h & 3) << 1));
                ((uint2*)&Pan[nxt][0][0])[i8] = make_uint2(h01, h23);
                ((uint2*)&Pan[nxt][1][0])[i8] = make_uint2(l01, l23);
            }
        }
    }

    // Y' -> bounce LDS, split to bf16 hi/lo, layout [l-mode][h] (136-padded)
#pragma unroll
    for (int hh = 0; hh < 2; ++hh) {
#pragma unroll
        for (int lt = 0; lt < 2; ++lt) {
            int lmode = lt * 16 + l15;            // D col = lane&15
            int h0 = hbase + hh * 16 + g * 4;     // D rows = 4*(lane>>4)+r
            f32x4 v = acc[hh][lt];
            unsigned hi01, lo01, hi23, lo23;
            split2(v[0], v[1], hi01, lo01);
            split2(v[2], v[3], hi23, lo23);
            ((uint2*)&Ybf[0][0])[lmode * 34 + (h0 >> 2)] = make_uint2(hi01, hi23);
            ((uint2*)&Ybf[1][0])[lmode * 34 + (h0 >> 2)] = make_uint2(lo01, lo23);
        }
    }
    __syncthreads();

    // step 2: one 16x16 tile per wave: (kt, lt2)
    const int kt = wid >> 1, lt2 = wid & 1;
    f32x4 z = {};
#pragma unroll
    for (int s2 = 0; s2 < 4; ++s2) {
        int aidx = (kt * 4 + s2) * 64 + lane;
        bf16x8 Ah = ((const bf16x8*)MFH)[aidx];
        bf16x8 Al = ((const bf16x8*)MFL)[aidx];
        int lmode = lt2 * 16 + l15;
        int yidx = lmode * 17 + s2 * 4 + g;       // short8 units, 16B aligned
        bf16x8 Yh = ((const bf16x8*)&Ybf[0][0])[yidx];
        bf16x8 Yl = ((const bf16x8*)&Ybf[1][0])[yidx];
        z = __builtin_amdgcn_mfma_f32_16x16x32_bf16(Ah, Yh, z, 0, 0, 0);
        z = __builtin_amdgcn_mfma_f32_16x16x32_bf16(Ah, Yl, z, 0, 0, 0);
        z = __builtin_amdgcn_mfma_f32_16x16x32_bf16(Al, Yh, z, 0, 0, 0);
    }
    float* op = Xh + (size_t)bc * 1024;
#pragma unroll
    for (int r = 0; r < 4; ++r)
        op[(kt * 16 + g * 4 + r) * 32 + lt2 * 16 + l15] = z[r];
}

// Transpose Xh[(b*64+i)][m] -> Xh_t[m][i*32+b].  2048 blocks: (i, m-tile).
__global__ __launch_bounds__(256) void t_xh(const float* __restrict__ Xh,
                                            float* __restrict__ Xh_t) {
    __shared__ float tile[32][33];
    const int i  = blockIdx.x & 63;
    const int mt = blockIdx.x >> 6;
    const int tx = threadIdx.x & 31;
    const int ty = threadIdx.x >> 5;
#pragma unroll
    for (int j = 0; j < 4; ++j) {
        int b = ty + 8 * j;
        tile[b][tx] = Xh[(b * 64 + i) * 1024 + mt * 32 + tx];
    }
    __syncthreads();
#pragma unroll
    for (int j = 0; j < 4; ++j) {
        int row = ty + 8 * j;
        Xh_t[(mt * 32 + row) * 2048 + i * 32 + tx] = tile[tx][row];
    }
}

// Mix, pair-block: block = mode-pair (m, nm). Outputs BOTH modes:
//   out[m]  = x1*We + x1n*Wo,  out[nm] = x1n*We - x1*Wo
__global__ __launch_bounds__(256) void k_mix4(const float* __restrict__ Xh_t,
                                              const float* __restrict__ Wt,
                                              float* __restrict__ blk_t) {
    const int m  = blockIdx.x;
    const int xm = m >> 5, ym = m & 31;
    const int nm = (((32 - xm) & 31) << 5) | ((32 - ym) & 31);
    if (m > nm) return;
    const int t = threadIdx.x;

    __shared__ float Xs[2][64][32];

    {
        const float4* xm4 = (const float4*)(Xh_t + m * 2048);
        const float4* xn4 = (const float4*)(Xh_t + nm * 2048);
        float4* s0 = (float4*)&Xs[0][0][0];
        float4* s1 = (float4*)&Xs[1][0][0];
        s0[t]       = xm4[t];
        s0[t + 256] = xm4[t + 256];
        s1[t]       = xn4[t];
        s1[t + 256] = xn4[t + 256];
    }
    __syncthreads();

    const int o  = t & 63;
    const int bq = t >> 6;
    const float* wpm = Wt + m * 4096 + o;
    const float* wpn = Wt + nm * 4096 + o;

    float am[8], an[8];
#pragma unroll
    for (int j = 0; j < 8; ++j) { am[j] = 0.f; an[j] = 0.f; }

#pragma unroll 4
    for (int i = 0; i < 64; ++i) {
        float wm = wpm[i * 64];
        float wn = wpn[i * 64];
        float we = 0.5f * (wm + wn);
        float wo = 0.5f * (wm - wn);
        const float* xr  = &Xs[0][i][bq * 8];
        const float* xrn = &Xs[1][i][bq * 8];
#pragma unroll
        for (int j = 0; j < 8; ++j) {
            float x1  = xr[j];
            float x1n = xrn[j];
            am[j] = fmaf(x1, we, fmaf(x1n, wo, am[j]));
            an[j] = fmaf(x1n, we, fmaf(x1, -wo, an[j]));
        }
    }

    float* om = blk_t + m * 2048 + o;
    float* on = blk_t + nm * 2048 + o;
#pragma unroll
    for (int j = 0; j < 8; ++j) {
        int b = bq * 8 + j;
        om[b * 64] = am[j];
        on[b * 64] = an[j];
    }
}

// Transpose blk_t[m][bo] -> blk[bo][m].
__global__ __launch_bounds__(256) void t_blk(const float* __restrict__ blk_t,
                                             float* __restrict__ blk) {
    __shared__ float tile[32][33];
    const int mt  = blockIdx.x & 31;
    const int bot = blockIdx.x >> 5;
    const int tx = threadIdx.x & 31;
    const int ty = threadIdx.x >> 5;
#pragma unroll
    for (int j = 0; j < 4; ++j) {
        int r = ty + 8 * j;
        tile[r][tx] = blk_t[(mt * 32 + r) * 2048 + bot * 32 + tx];
    }
    __syncthreads();
#pragma unroll
    for (int j = 0; j < 4; ++j) {
        int r = ty + 8 * j;
        blk[(bot * 32 + r) * 1024 + mt * 32 + tx] = tile[tx][r];
    }
}

// Inverse: per (b,o) block: T = (1/16384) M32c * blk;  out = T * M32c^T
__global__ __launch_bounds__(256) void k_inv(const float* __restrict__ blk,
                                             const float* __restrict__ M,
                                             const float* __restrict__ MT,
                                             float* __restrict__ out) {
    const int bo = blockIdx.x;
    const int t  = threadIdx.x;
    __shared__ float smem[8448];
    float* Mcs  = smem;
    float* Ts   = smem + 4224;
    float* outS = smem;

#pragma unroll
    for (int j = 0; j < 16; ++j) {
        int idx = t + j * 256;
        int r = idx >> 5, h = idx & 31;
        Mcs[r * 33 + h] = M[r * 128 + h] * (1.f / 16384.f);
    }
    __syncthreads();

    const int r  = t & 127;
    const int rh = __builtin_amdgcn_readfirstlane(t >> 7);

    {
        const float* bp = blk + (size_t)bo * (MD * MD);
        float acc[16];
#pragma unroll
        for (int j = 0; j < 16; ++j) acc[j] = 0.f;
#pragma unroll 4
        for (int h = 0; h < MD; ++h) {
            float mc = Mcs[r * 33 + h];
            const float* brow = bp + h * MD + rh * 16;
#pragma unroll
            for (int j = 0; j < 16; ++j)
                acc[j] = fmaf(brow[j], mc, acc[j]);
        }
#pragma unroll
        for (int j = 0; j < 16; ++j) Ts[r * 33 + rh * 16 + j] = acc[j];
    }
    __syncthreads();

    float acc[64];
#pragma unroll
    for (int j = 0; j < 64; ++j) acc[j] = 0.f;
#pragma unroll 2
    for (int l = 0; l < MD; ++l) {
        float tv = Ts[r * 33 + l];
        const float* mt = MT + l * 128 + rh * 64;
#pragma unroll
        for (int j = 0; j < 64; ++j)
            acc[j] = fmaf(mt[j], tv, acc[j]);
    }

    float* op = out + (size_t)bo * (SS * SS);
    for (int rr = 0; rr < 2; ++rr) {
        __syncthreads();
        if (rh == rr) {
#pragma unroll
            for (int j = 0; j < 64; ++j) outS[r * 65 + j] = acc[j];
        }
        __syncthreads();
        const int cc = t & 63;
        const int r0 = t >> 6;
#pragma unroll
        for (int j = 0; j < 32; ++j) {
            int rrow = r0 + 4 * j;
            op[rrow * SS + rr * 64 + cc] = outS[rrow * 65 + cc];
        }
    }
}

extern "C" void kernel_launch(void* const* d_in, const int* in_sizes, int n_in,
                              void* d_out, int out_size, void* d_ws, size_t ws_size,
                              hipStream_t stream) {
    const float* x   = (const float*)d_in[0];
    const float* wgt = (const float*)d_in[1];
    float* outp = (float*)d_out;
    float* ws   = (float*)d_ws;

    float* M     = ws + OFF_M;
    float* MT    = ws + OFF_MT;
    float* Xh    = ws + OFF_XH;
    float* Xh_t  = ws + OFF_XHT;
    float* Wt    = ws + OFF_WT;
    float* blk_t = ws + OFF_BLKT;
    float* blk   = ws + OFF_BLK;
    unsigned short* MFH = (unsigned short*)(ws + OFF_MFH);
    unsigned short* MFL = (unsigned short*)(ws + OFF_MFL);

    k_prep <<<4176, 256, 0, stream>>>(wgt, M, MT, Wt, MFH, MFL);
    k_fwd2 <<<2048, 256, 0, stream>>>(x, MFH, MFL, Xh);
    t_xh   <<<2048, 256, 0, stream>>>(Xh, Xh_t);
    k_mix4 <<<1024, 256, 0, stream>>>(Xh_t, Wt, blk_t);
    t_blk  <<<2048, 256, 0, stream>>>(blk_t, blk);
    k_inv  <<<2048, 256, 0, stream>>>(blk, M, MT, outp);
}

// Round 7
// 108.194 us; speedup vs baseline: 1.4830x; 1.1315x over previous
//
#include <hip/hip_runtime.h>
#include <math.h>

// SpectralConv2d: out = idht2( mix( dht2(x)[:, :, :32, :32], W ) ) / S^2
// x:  [32][64][128][128] f32   weights1: [64][64][32][32] f32
// out:[32][64][128][128] f32
//
// M is the recursive pseudo-Hartley operator (NOT plain cas(2pi kn/N)):
//   M[k,n] = prod over levels (size Nj = 128,64,...,2):
//     if bit_j(n): (k_j < Nj/2 ? +1 : -1) * cas(2*pi*(k_j mod Nj/2)/Nj), else 1
//     with k_{j+1} = k_j mod (Nj/2).
//
// Pipeline: k_prep (W-transpose + bf16 hi/lo MFMA fragment table, tt=0..7) ->
//   k_fwd2 (MFMA: Y' = X*M32^T then Z = M32*Y') -> t_xh -> k_mix4 ->
//   t_blk -> k_inv2 (MFMA: T = Mc*blk/16384, out^T-tiles = M-frag * T^T,
//   float4 direct stores).

#define SS   128
#define MD   32
#define NBAT 32
#define CI   64
#define CO   64

#define TWO_PI 6.2831853071795864769

typedef __attribute__((ext_vector_type(8))) short bf16x8;
typedef __attribute__((ext_vector_type(4))) float f32x4;

// ws layout (floats). blk_t aliases Xh; blk aliases Xh_t. ~33.7 MB.
static const size_t OFF_XH   = 32768;                    // 2048*1024
static const size_t OFF_XHT  = 32768 + 2097152;          // 2048*1024
static const size_t OFF_WT   = 32768 + 2 * 2097152;      // 4096*1024
static const size_t OFF_BLKT = OFF_XH;                   // alias
static const size_t OFF_BLK  = OFF_XHT;                  // alias
static const size_t OFF_MFH  = OFF_WT + 4194304;         // 16384 ushort = 8192 floats
static const size_t OFF_MFL  = OFF_MFH + 8192;           // 16384 ushort

__device__ inline float m_entry(int k, int n) {
    float prod = 1.f;
    int kk = k, nn = n;
    for (int Nj = SS; Nj > 1; Nj >>= 1) {
        int half = Nj >> 1;
        int k1 = kk & (half - 1);
        if (nn & 1) {
            double ang = (TWO_PI / (double)Nj) * (double)k1;
            float cas = (float)(cos(ang) + sin(ang));
            prod *= (kk < half) ? cas : -cas;
        }
        kk = k1;
        nn >>= 1;
    }
    return prod;
}

__device__ inline unsigned short f2bf(float f) {
    unsigned u = __float_as_uint(f);
    return (unsigned short)((u + 0x7FFF + ((u >> 16) & 1)) >> 16);
}
__device__ inline float bf2f(unsigned short h) {
    return __uint_as_float((unsigned)h << 16);
}
__device__ inline void split2(float a, float b, unsigned& hi, unsigned& lo) {
    unsigned short ah = f2bf(a), bh = f2bf(b);
    hi = (unsigned)ah | ((unsigned)bh << 16);
    lo = (unsigned)f2bf(a - bf2f(ah)) | ((unsigned)f2bf(b - bf2f(bh)) << 16);
}

// blocks 0..4095: transpose wgt[(i*64+o)][m] -> Wt[m][i*64+o] in 32x32 tiles.
// blocks 4096..4159: MFMA fragment table for M (bf16 hi/lo):
//   entry(tt,s,lane,j) = M[tt*16 + (lane&15)][s*32 + (lane>>4)*8 + j]
//   Serves: k_fwd2 step-1 B (tt=0..1,s=0..3), k_fwd2 step-2 A (tt=0..1,s=0..3),
//           k_inv2 step-1 A and step-2 A (tt=0..7, s=0).
__global__ __launch_bounds__(256) void k_prep(const float* __restrict__ wgt,
                                              float* __restrict__ Wt,
                                              unsigned short* __restrict__ MFH,
                                              unsigned short* __restrict__ MFL) {
    const int bid = blockIdx.x;
    const int t   = threadIdx.x;
    if (bid >= 4096) {
        int idx2 = (bid - 4096) * 256 + t;       // 0..16383
        int j    = idx2 & 7;
        int lane = (idx2 >> 3) & 63;
        int s    = (idx2 >> 9) & 3;
        int tt   = idx2 >> 11;                   // 0..7
        int kq   = tt * 16 + (lane & 15);
        int nq   = s * 32 + ((lane >> 4) << 3) + j;
        float f  = m_entry(kq, nq);
        unsigned short hi = f2bf(f);
        MFH[idx2] = hi;
        MFL[idx2] = f2bf(f - bf2f(hi));
        return;
    }
    __shared__ float tile[32][33];
    const int mt  = bid & 31;
    const int iot = bid >> 5;
    const int tx = t & 31;
    const int ty = t >> 5;
#pragma unroll
    for (int j = 0; j < 4; ++j) {
        int r = ty + 8 * j;
        tile[r][tx] = wgt[(iot * 32 + r) * 1024 + mt * 32 + tx];
    }
    __syncthreads();
#pragma unroll
    for (int j = 0; j < 4; ++j) {
        int r = ty + 8 * j;
        Wt[(mt * 32 + r) * 4096 + iot * 32 + tx] = tile[tx][r];
    }
}

// Forward via MFMA bf16 hi/lo split. Per block = one (b,c) plane.
//   step 1: Y'[h][l] = sum_w X[h][w] * M32[l][w]   (K=w, A=X contiguous-K)
//   step 2: Z[k][l]  = sum_h M32[k][h] * Y'[h][l]  (K=h, A=M table, B=Y bounce)
__global__ __launch_bounds__(256, 3) void k_fwd2(const float* __restrict__ x,
                                                 const unsigned short* __restrict__ MFH,
                                                 const unsigned short* __restrict__ MFL,
                                                 float* __restrict__ Xh) {
    const int bc = blockIdx.x;
    const float* xp = x + (size_t)bc * 16384;
    const int t = threadIdx.x;
    const int lane = t & 63, wid = t >> 6;
    const int l15 = lane & 15, g = lane >> 4;

    __shared__ unsigned short Pan[2][2][4096];   // [buf][hi/lo], swizzled [h][w']
    __shared__ unsigned short Ybf[2][32 * 136];  // [hi/lo][l][136 h-slots]

    const int sh0 = t >> 3, swq = t & 7;         // staging coords

    {   // stage panel 0
#pragma unroll
        for (int q = 0; q < 4; ++q) {
            int h = sh0 + 32 * q;
            float4 v = *(const float4*)(xp + h * 128 + swq * 4);
            unsigned h01, l01, h23, l23;
            split2(v.x, v.y, h01, l01);
            split2(v.z, v.w, h23, l23);
            int i8 = h * 8 + (swq ^ ((h & 3) << 1));
            ((uint2*)&Pan[0][0][0])[i8] = make_uint2(h01, h23);
            ((uint2*)&Pan[0][1][0])[i8] = make_uint2(l01, l23);
        }
    }

    f32x4 acc[2][2] = {};                        // [hh][lt]
    const int hbase = wid * 32;

    for (int s = 0; s < 4; ++s) {
        __syncthreads();
        const int cur = s & 1, nxt = cur ^ 1;
        float4 pre[4];
        if (s < 3) {                              // issue next-panel loads early
#pragma unroll
            for (int q = 0; q < 4; ++q)
                pre[q] = *(const float4*)(xp + (sh0 + 32 * q) * 128 + (s + 1) * 32 + swq * 4);
        }
        bf16x8 Bh[2], Bl[2];
#pragma unroll
        for (int lt = 0; lt < 2; ++lt) {
            int bidx = (lt * 4 + s) * 64 + lane;  // L1-hot table
            Bh[lt] = ((const bf16x8*)MFH)[bidx];
            Bl[lt] = ((const bf16x8*)MFL)[bidx];
        }
#pragma unroll
        for (int hh = 0; hh < 2; ++hh) {
            int h = hbase + hh * 16 + l15;
            int aidx = h * 4 + (g ^ (h & 3));     // swizzled b128
            bf16x8 Ah = ((const bf16x8*)&Pan[cur][0][0])[aidx];
            bf16x8 Al = ((const bf16x8*)&Pan[cur][1][0])[aidx];
#pragma unroll
            for (int lt = 0; lt < 2; ++lt) {
                acc[hh][lt] = __builtin_amdgcn_mfma_f32_16x16x32_bf16(Ah, Bh[lt], acc[hh][lt], 0, 0, 0);
                acc[hh][lt] = __builtin_amdgcn_mfma_f32_16x16x32_bf16(Ah, Bl[lt], acc[hh][lt], 0, 0, 0);
                acc[hh][lt] = __builtin_amdgcn_mfma_f32_16x16x32_bf16(Al, Bh[lt], acc[hh][lt], 0, 0, 0);
            }
        }
        if (s < 3) {                              // write next panel
#pragma unroll
            for (int q = 0; q < 4; ++q) {
                int h = sh0 + 32 * q;
                unsigned h01, l01, h23, l23;
                split2(pre[q].x, pre[q].y, h01, l01);
                split2(pre[q].z, pre[q].w, h23, l23);
                int i8 = h * 8 + (swq ^ ((h & 3) << 1));
                ((uint2*)&Pan[nxt][0][0])[i8] = make_uint2(h01, h23);
                ((uint2*)&Pan[nxt][1][0])[i8] = make_uint2(l01, l23);
            }
        }
    }

    // Y' -> bounce LDS, split to bf16 hi/lo, layout [l-mode][h] (136-padded)
#pragma unroll
    for (int hh = 0; hh < 2; ++hh) {
#pragma unroll
        for (int lt = 0; lt < 2; ++lt) {
            int lmode = lt * 16 + l15;            // D col = lane&15
            int h0 = hbase + hh * 16 + g * 4;     // D rows = 4*(lane>>4)+r
            f32x4 v = acc[hh][lt];
            unsigned hi01, lo01, hi23, lo23;
            split2(v[0], v[1], hi01, lo01);
            split2(v[2], v[3], hi23, lo23);
            ((uint2*)&Ybf[0][0])[lmode * 34 + (h0 >> 2)] = make_uint2(hi01, hi23);
            ((uint2*)&Ybf[1][0])[lmode * 34 + (h0 >> 2)] = make_uint2(lo01, lo23);
        }
    }
    __syncthreads();

    // step 2: one 16x16 tile per wave: (kt, lt2)
    const int kt = wid >> 1, lt2 = wid & 1;
    f32x4 z = {};
#pragma unroll
    for (int s2 = 0; s2 < 4; ++s2) {
        int aidx = (kt * 4 + s2) * 64 + lane;
        bf16x8 Ah = ((const bf16x8*)MFH)[aidx];
        bf16x8 Al = ((const bf16x8*)MFL)[aidx];
        int lmode = lt2 * 16 + l15;
        int yidx = lmode * 17 + s2 * 4 + g;       // short8 units, 16B aligned
        bf16x8 Yh = ((const bf16x8*)&Ybf[0][0])[yidx];
        bf16x8 Yl = ((const bf16x8*)&Ybf[1][0])[yidx];
        z = __builtin_amdgcn_mfma_f32_16x16x32_bf16(Ah, Yh, z, 0, 0, 0);
        z = __builtin_amdgcn_mfma_f32_16x16x32_bf16(Ah, Yl, z, 0, 0, 0);
        z = __builtin_amdgcn_mfma_f32_16x16x32_bf16(Al, Yh, z, 0, 0, 0);
    }
    float* op = Xh + (size_t)bc * 1024;
#pragma unroll
    for (int r = 0; r < 4; ++r)
        op[(kt * 16 + g * 4 + r) * 32 + lt2 * 16 + l15] = z[r];
}

// Transpose Xh[(b*64+i)][m] -> Xh_t[m][i*32+b].  2048 blocks: (i, m-tile).
__global__ __launch_bounds__(256) void t_xh(const float* __restrict__ Xh,
                                            float* __restrict__ Xh_t) {
    __shared__ float tile[32][33];
    const int i  = blockIdx.x & 63;
    const int mt = blockIdx.x >> 6;
    const int tx = threadIdx.x & 31;
    const int ty = threadIdx.x >> 5;
#pragma unroll
    for (int j = 0; j < 4; ++j) {
        int b = ty + 8 * j;
        tile[b][tx] = Xh[(b * 64 + i) * 1024 + mt * 32 + tx];
    }
    __syncthreads();
#pragma unroll
    for (int j = 0; j < 4; ++j) {
        int row = ty + 8 * j;
        Xh_t[(mt * 32 + row) * 2048 + i * 32 + tx] = tile[tx][row];
    }
}

// Mix, pair-block: block = mode-pair (m, nm). Outputs BOTH modes:
//   out[m]  = x1*We + x1n*Wo,  out[nm] = x1n*We - x1*Wo
__global__ __launch_bounds__(256) void k_mix4(const float* __restrict__ Xh_t,
                                              const float* __restrict__ Wt,
                                              float* __restrict__ blk_t) {
    const int m  = blockIdx.x;
    const int xm = m >> 5, ym = m & 31;
    const int nm = (((32 - xm) & 31) << 5) | ((32 - ym) & 31);
    if (m > nm) return;
    const int t = threadIdx.x;

    __shared__ float Xs[2][64][32];

    {
        const float4* xm4 = (const float4*)(Xh_t + m * 2048);
        const float4* xn4 = (const float4*)(Xh_t + nm * 2048);
        float4* s0 = (float4*)&Xs[0][0][0];
        float4* s1 = (float4*)&Xs[1][0][0];
        s0[t]       = xm4[t];
        s0[t + 256] = xm4[t + 256];
        s1[t]       = xn4[t];
        s1[t + 256] = xn4[t + 256];
    }
    __syncthreads();

    const int o  = t & 63;
    const int bq = t >> 6;
    const float* wpm = Wt + m * 4096 + o;
    const float* wpn = Wt + nm * 4096 + o;

    float am[8], an[8];
#pragma unroll
    for (int j = 0; j < 8; ++j) { am[j] = 0.f; an[j] = 0.f; }

#pragma unroll 4
    for (int i = 0; i < 64; ++i) {
        float wm = wpm[i * 64];
        float wn = wpn[i * 64];
        float we = 0.5f * (wm + wn);
        float wo = 0.5f * (wm - wn);
        const float* xr  = &Xs[0][i][bq * 8];
        const float* xrn = &Xs[1][i][bq * 8];
#pragma unroll
        for (int j = 0; j < 8; ++j) {
            float x1  = xr[j];
            float x1n = xrn[j];
            am[j] = fmaf(x1, we, fmaf(x1n, wo, am[j]));
            an[j] = fmaf(x1n, we, fmaf(x1, -wo, an[j]));
        }
    }

    float* om = blk_t + m * 2048 + o;
    float* on = blk_t + nm * 2048 + o;
#pragma unroll
    for (int j = 0; j < 8; ++j) {
        int b = bq * 8 + j;
        om[b * 64] = am[j];
        on[b * 64] = an[j];
    }
}

// Transpose blk_t[m][bo] -> blk[bo][m].
__global__ __launch_bounds__(256) void t_blk(const float* __restrict__ blk_t,
                                             float* __restrict__ blk) {
    __shared__ float tile[32][33];
    const int mt  = blockIdx.x & 31;
    const int bot = blockIdx.x >> 5;
    const int tx = threadIdx.x & 31;
    const int ty = threadIdx.x >> 5;
#pragma unroll
    for (int j = 0; j < 4; ++j) {
        int r = ty + 8 * j;
        tile[r][tx] = blk_t[(mt * 32 + r) * 2048 + bot * 32 + tx];
    }
    __syncthreads();
#pragma unroll
    for (int j = 0; j < 4; ++j) {
        int r = ty + 8 * j;
        blk[(bot * 32 + r) * 1024 + mt * 32 + tx] = tile[tx][r];
    }
}

// Inverse via MFMA, per (b,o) block (4 waves):
//   step 1: T[r][l] = sum_{h<32} M[r][h] * (blk[h][l]/16384)   r<128, l<32
//           A = M-frag table (tt=0..7, s=0);  B = blk^T staged in LDS.
//   step 2: out[r][c] = sum_{l<32} T[r][l] * M[c][l]
//           computed as out^T tiles: A = M-frag table (tt=ct,s=0), B = T^T
//           from LDS; D regs (ri) are contiguous in c -> direct float4 store.
__global__ __launch_bounds__(256, 2) void k_inv2(const float* __restrict__ blk,
                                                 const unsigned short* __restrict__ MFH,
                                                 const unsigned short* __restrict__ MFL,
                                                 float* __restrict__ out) {
    const int bo = blockIdx.x;
    const int t  = threadIdx.x;
    const int lane = t & 63, wid = t >> 6;
    const int l15 = lane & 15, g = lane >> 4;

    __shared__ __align__(16) unsigned short Bst[2][32 * 40];   // blk^T bf16 [l][h]
    __shared__ __align__(16) unsigned short Tl[2][128 * 40];   // T bf16 [r][l]

    {   // stage blk^T, scaled by 1/16384, split hi/lo
        float4 v = ((const float4*)(blk + (size_t)bo * 1024))[t];
        const int h = t >> 3, l0 = (t & 7) * 4;
        float vv[4] = { v.x * (1.f / 16384.f), v.y * (1.f / 16384.f),
                        v.z * (1.f / 16384.f), v.w * (1.f / 16384.f) };
#pragma unroll
        for (int q = 0; q < 4; ++q) {
            unsigned short hi = f2bf(vv[q]);
            Bst[0][(l0 + q) * 40 + h] = hi;
            Bst[1][(l0 + q) * 40 + h] = f2bf(vv[q] - bf2f(hi));
        }
    }
    __syncthreads();

    // step 1: wave wid owns T rows [wid*32, wid*32+32)
#pragma unroll
    for (int rr = 0; rr < 2; ++rr) {
        const int tt = wid * 2 + rr;
        const int aidx = (tt * 4) * 64 + lane;
        bf16x8 Ah = ((const bf16x8*)MFH)[aidx];
        bf16x8 Al = ((const bf16x8*)MFL)[aidx];
#pragma unroll
        for (int lt = 0; lt < 2; ++lt) {
            bf16x8 Bh = *(const bf16x8*)&Bst[0][(lt * 16 + l15) * 40 + g * 8];
            bf16x8 Bl = *(const bf16x8*)&Bst[1][(lt * 16 + l15) * 40 + g * 8];
            f32x4 acc = {};
            acc = __builtin_amdgcn_mfma_f32_16x16x32_bf16(Ah, Bh, acc, 0, 0, 0);
            acc = __builtin_amdgcn_mfma_f32_16x16x32_bf16(Al, Bh, acc, 0, 0, 0);
            acc = __builtin_amdgcn_mfma_f32_16x16x32_bf16(Ah, Bl, acc, 0, 0, 0);
            // D: lane holds T[tt*16 + g*4 + ri][lt*16 + l15]
#pragma unroll
            for (int ri = 0; ri < 4; ++ri) {
                int r = tt * 16 + g * 4 + ri;
                int l = lt * 16 + l15;
                unsigned short hi = f2bf(acc[ri]);
                Tl[0][r * 40 + l] = hi;
                Tl[1][r * 40 + l] = f2bf(acc[ri] - bf2f(hi));
            }
        }
    }
    __syncthreads();

    // step 2: wave wid owns out rows r in [wid*32, wid*32+32); all c.
    float* op = out + (size_t)bo * (SS * SS);
#pragma unroll
    for (int rr = 0; rr < 2; ++rr) {
        const int rt = wid * 2 + rr;
        // B = T^T: col index r = rt*16 + l15, k = l = g*8+j
        bf16x8 Bh = *(const bf16x8*)&Tl[0][(rt * 16 + l15) * 40 + g * 8];
        bf16x8 Bl = *(const bf16x8*)&Tl[1][(rt * 16 + l15) * 40 + g * 8];
        const int r = rt * 16 + l15;
#pragma unroll
        for (int ct = 0; ct < 8; ++ct) {
            const int aidx = (ct * 4) * 64 + lane;    // L1-hot table
            bf16x8 Ah = ((const bf16x8*)MFH)[aidx];
            bf16x8 Al = ((const bf16x8*)MFL)[aidx];
            f32x4 acc = {};
            acc = __builtin_amdgcn_mfma_f32_16x16x32_bf16(Ah, Bh, acc, 0, 0, 0);
            acc = __builtin_amdgcn_mfma_f32_16x16x32_bf16(Al, Bh, acc, 0, 0, 0);
            acc = __builtin_amdgcn_mfma_f32_16x16x32_bf16(Ah, Bl, acc, 0, 0, 0);
            // D: lane holds out[r][ct*16 + g*4 + ri], ri contiguous in c
            *(float4*)&op[r * SS + ct * 16 + g * 4] =
                make_float4(acc[0], acc[1], acc[2], acc[3]);
        }
    }
}

extern "C" void kernel_launch(void* const* d_in, const int* in_sizes, int n_in,
                              void* d_out, int out_size, void* d_ws, size_t ws_size,
                              hipStream_t stream) {
    const float* x   = (const float*)d_in[0];
    const float* wgt = (const float*)d_in[1];
    float* outp = (float*)d_out;
    float* ws   = (float*)d_ws;

    float* Xh    = ws + OFF_XH;
    float* Xh_t  = ws + OFF_XHT;
    float* Wt    = ws + OFF_WT;
    float* blk_t = ws + OFF_BLKT;
    float* blk   = ws + OFF_BLK;
    unsigned short* MFH = (unsigned short*)(ws + OFF_MFH);
    unsigned short* MFL = (unsigned short*)(ws + OFF_MFL);

    k_prep <<<4160, 256, 0, stream>>>(wgt, Wt, MFH, MFL);
    k_fwd2 <<<2048, 256, 0, stream>>>(x, MFH, MFL, Xh);
    t_xh   <<<2048, 256, 0, stream>>>(Xh, Xh_t);
    k_mix4 <<<1024, 256, 0, stream>>>(Xh_t, Wt, blk_t);
    t_blk  <<<2048, 256, 0, stream>>>(blk_t, blk);
    k_inv2 <<<2048, 256, 0, stream>>>(blk, MFH, MFL, outp);
}